// Round 3
// baseline (942.279 us; speedup 1.0000x reference)
//
#include <hip/hip_runtime.h>
#include <stdint.h>

#define M_DIM 2048
#define N_DIM 4096
#define K_DIM 11008
#define NN    11008
#define KTOK  2201    // int(11008*0.2)
#define NSEL  4403    // int(11008*0.4)
#define NCHUNK 43     // 43*256 == 11008
#define NBINS 2049    // counts in [0,2048]
#define NWORDS 344    // 11008/32 mask words per row
#define NC64  172     // 11008/64 ballot chunks per row

typedef __bf16 bf16x8_t __attribute__((ext_vector_type(8)));
typedef float  f32x4_t  __attribute__((ext_vector_type(4)));

__device__ __forceinline__ unsigned short f2bf(float f) {
  unsigned u = __float_as_uint(f);
  u = (u + 0x7FFFu + ((u >> 16) & 1u)) >> 16;   // round-to-nearest-even
  return (unsigned short)u;
}

__device__ __forceinline__ unsigned fkey(unsigned v) {
  return v ^ ((unsigned)((int)v >> 31) | 0x80000000u);
}

// ---------------- f32 -> bf16 conversion (vectorized) ----------------
__global__ __launch_bounds__(256) void cvt_f32_bf16(const float4* __restrict__ src,
                                                    ushort4* __restrict__ dst, int n4) {
  int i = blockIdx.x * 256 + threadIdx.x;
  int stride = gridDim.x * 256;
  for (; i < n4; i += stride) {
    float4 v = src[i];
    ushort4 o;
    o.x = f2bf(v.x); o.y = f2bf(v.y); o.z = f2bf(v.z); o.w = f2bf(v.w);
    dst[i] = o;
  }
}

// ---------------- per-row top-KTOK -> per-row bitmask (radix select) ---------
// v3: register-resident keys. Each thread holds 43 keys (layout i = j*256+t),
// loaded from global ONCE. All radix passes + ballot passes run on registers.
// Mapping for ballots: chunk c = 4*it + w -> key index c*64+lane = it*256 +
// (w*64+lane) = kreg[it] of thread t=w*64+lane (static index, rule 20).
__global__ __launch_bounds__(256) void topk_rows(const float* __restrict__ x,
                                                 unsigned* __restrict__ maskT) {
  __shared__ int hist[2048];        // 8192 B
  __shared__ int wtot[4];
  __shared__ int eqpre[NC64];
  __shared__ int eqex[NC64];
  __shared__ unsigned s_band;
  __shared__ int s_kneed;

  const int t = threadIdx.x;
  const int lane = t & 63;
  const int w = t >> 6;
  const int r = blockIdx.x;
  const unsigned* __restrict__ rowu = (const unsigned*)(x + (size_t)r * NN);

  unsigned kreg[43];
#pragma unroll
  for (int j = 0; j < 43; ++j) kreg[j] = fkey(rowu[j * 256 + t]);

  // ---- 3-pass radix select for the KTOK-th largest key ----
  unsigned band_prefix = 0;
  int kneed = KTOK;

  for (int pass = 0; pass < 3; ++pass) {
    const int bins  = (pass == 2) ? 1024 : 2048;

    for (int i = t; i < bins; i += 256) hist[i] = 0;
    __syncthreads();

    if (pass == 0) {
#pragma unroll
      for (int j = 0; j < 43; ++j) atomicAdd(&hist[kreg[j] >> 21], 1);
    } else if (pass == 1) {
#pragma unroll
      for (int j = 0; j < 43; ++j) {
        unsigned k = kreg[j];
        if ((k >> 21) == band_prefix) atomicAdd(&hist[(k >> 10) & 2047u], 1);
      }
    } else {
#pragma unroll
      for (int j = 0; j < 43; ++j) {
        unsigned k = kreg[j];
        if ((k >> 10) == band_prefix) atomicAdd(&hist[k & 1023u], 1);
      }
    }
    __syncthreads();

    // parallel suffix-select: thread t owns 8 bins [8t, 8t+8)
    const int nch = bins / 8;      // 256 (passes 0,1) or 128 (pass 2)
    const int nw  = nch >> 6;
    int loc = 0;
    if (t < nch) {
#pragma unroll
      for (int v = 0; v < 8; ++v) loc += hist[t * 8 + v];
    }
    int incl = loc;
#pragma unroll
    for (int d = 1; d < 64; d <<= 1) {
      int o = __shfl_down(incl, d);
      if (lane + d < 64) incl += o;
    }
    if (w < nw && lane == 0) wtot[w] = incl;
    __syncthreads();
    int wsuf = 0;
    for (int u = w + 1; u < nw; ++u) wsuf += wtot[u];
    const int suf_ex = wsuf + (incl - loc);
    if (t < nch && suf_ex < kneed && suf_ex + loc >= kneed) {
      int run = suf_ex;
      for (int v = t * 8 + 7;; --v) {
        int h = hist[v];
        if (run + h >= kneed) { s_band = (unsigned)v; s_kneed = kneed - run; break; }
        run += h;
      }
    }
    __syncthreads();
    band_prefix = (pass == 0) ? s_band
                : (band_prefix << ((pass == 1) ? 11 : 10)) | s_band;
    kneed = s_kneed;
    __syncthreads();
  }

  const unsigned Tkey = band_prefix;   // exact KTOK-th largest key
  const int need = kneed;              // # equal-to-Tkey to take (lowest index first)

  // ---- per-chunk equal counts (ballot), then exclusive prefix ----
#pragma unroll
  for (int it = 0; it < 43; ++it) {
    const int c = 4 * it + w;
    unsigned long long eb = __ballot(kreg[it] == Tkey);
    if (lane == 0) eqpre[c] = __popcll(eb);
  }
  __syncthreads();
  if (t < NC64) {
    int s = 0;
    for (int c = 0; c < t; ++c) s += eqpre[c];
    eqex[t] = s;
  }
  __syncthreads();

  // ---- build mask words via ballot; stable tie-break toward lowest index ----
#pragma unroll
  for (int it = 0; it < 43; ++it) {
    const int c = 4 * it + w;
    const unsigned k = kreg[it];
    const bool eq = (k == Tkey);
    unsigned long long eb = __ballot(eq);
    int myrank = eqex[c] + __popcll(eb & ((1ull << lane) - 1ull));
    bool pred = (k > Tkey) || (eq && (myrank < need));
    unsigned long long pb = __ballot(pred);
    if (lane == 0) maskT[(size_t)(2 * c)     * M_DIM + r] = (unsigned)pb;
    if (lane == 1) maskT[(size_t)(2 * c + 1) * M_DIM + r] = (unsigned)(pb >> 32);
  }
}

// ---------------- bit-count votes: counts[n] = sum_r maskT bit ----------------
__global__ __launch_bounds__(256) void count_votes(const unsigned* __restrict__ maskT,
                                                   int* __restrict__ counts) {
  __shared__ int part[256 * 33];
  const int t = threadIdx.x;
  const int w = blockIdx.x;
  int c[32];
#pragma unroll
  for (int b = 0; b < 32; ++b) c[b] = 0;
  const unsigned* col = maskT + (size_t)w * M_DIM;
#pragma unroll
  for (int rep = 0; rep < M_DIM / 256; ++rep) {
    unsigned m = col[rep * 256 + t];
#pragma unroll
    for (int b = 0; b < 32; ++b) c[b] += (m >> b) & 1u;
  }
#pragma unroll
  for (int b = 0; b < 32; ++b) part[t * 33 + b] = c[b];
  __syncthreads();
  if (t < 32) {
    int s = 0;
    for (int j = 0; j < 256; ++j) s += part[j * 33 + t];
    counts[w * 32 + t] = s;
  }
}

// ---------------- stable counting sort of counts (desc value, asc index) ----------------
__global__ __launch_bounds__(256) void count_hist(const int* __restrict__ counts,
                                                  int* __restrict__ bhist,
                                                  int* __restrict__ rnk) {
  __shared__ int lc[256];
  __shared__ int lh[NBINS];
  const int b = blockIdx.x, t = threadIdx.x;
  const int n = b * 256 + t;
  const int c = counts[n];
  lc[t] = c;
  for (int i = t; i < NBINS; i += 256) lh[i] = 0;
  __syncthreads();
  atomicAdd(&lh[c], 1);
  __syncthreads();
  for (int i = t; i < NBINS; i += 256) bhist[b * NBINS + i] = lh[i];
  int rk = 0;
  for (int m = 0; m < t; ++m) rk += (lc[m] == c);
  rnk[n] = rk;
}

__global__ __launch_bounds__(256) void scan_hist(const int* __restrict__ bhist,
                                                 int* __restrict__ pre) {
  __shared__ int total[NBINS];
  __shared__ int sstart[NBINS];
  const int t = threadIdx.x;
  for (int c = t; c < NBINS; c += 256) {
    int s = 0;
    for (int h = 0; h < NCHUNK; ++h) s += bhist[h * NBINS + c];
    total[c] = s;
  }
  __syncthreads();
  if (t == 0) {
    int run = 0;
    for (int c = NBINS - 1; c >= 0; --c) { sstart[c] = run; run += total[c]; }
  }
  __syncthreads();
  for (int c = t; c < NBINS; c += 256) {
    int run = sstart[c];
    for (int h = 0; h < NCHUNK; ++h) { pre[h * NBINS + c] = run; run += bhist[h * NBINS + c]; }
  }
}

// place v2: writes inverse map posn[n] = output column (or -1 if not selected)
__global__ __launch_bounds__(256) void place(const int* __restrict__ counts,
                                             const int* __restrict__ rnk,
                                             const int* __restrict__ pre,
                                             int* __restrict__ posn) {
  const int b = blockIdx.x, t = threadIdx.x;
  const int n = b * 256 + t;
  const int c = counts[n];
  const int pos = pre[b * NBINS + c] + rnk[n];
  posn[n] = (pos < NSEL) ? pos : -1;
}

// ---------------- scatter filtered_W: coalesced row read, scattered write ----
__global__ __launch_bounds__(256) void scatter_w(const float4* __restrict__ w4,
                                                 const int4* __restrict__ posn4,
                                                 float* __restrict__ out) {
  const int d = blockIdx.x;
  const int t = threadIdx.x;
  float* od = out + (size_t)d * NSEL;
  const float4* wr = w4 + (size_t)d * (NN / 4);
  for (int i = t; i < NN / 4; i += 256) {
    float4 v = wr[i];
    int4 p = posn4[i];
    if (p.x >= 0) od[p.x] = v.x;
    if (p.y >= 0) od[p.y] = v.y;
    if (p.z >= 0) od[p.z] = v.z;
    if (p.w >= 0) od[p.w] = v.w;
  }
}

// ---------------- bf16 MFMA GEMM: C[M][N] = A[M][K] * B[N][K]^T ----------------
// v3: depth-3 counted-vmcnt pipeline (T3/T4). BK=32, FOUR LDS buffers (64 KB,
// 2 blocks/CU). Each iter: [B1 barrier: WAR guard] stage tile t+3 (4 loads),
// [s_waitcnt vmcnt(12): own tile-t loads landed, 3 tiles stay in flight]
// [B2 barrier: all waves' tile-t loads landed] compute tile t. No vmcnt(0)
// drain in the main loop -> loads get ~3 compute phases of latency cover.
// Swizzle for BK=32 (4 granule slots/row): slot = g ^ ((r>>1)&3), applied
// both sides (pre-swizzled global source; swizzled ds_read offset). Gives a
// uniform 8-lanes-per-bank-group b128 pattern (= the 0-conflict R1 profile).
#define BM 128
#define BN 128
#define BK 32
#define NTILES 344   // K_DIM / BK

__device__ __forceinline__ void async16(const void* g, void* l) {
  __builtin_amdgcn_global_load_lds(
      (const __attribute__((address_space(1))) void*)g,
      (__attribute__((address_space(3))) void*)l, 16, 0, 0);
}

__global__ __launch_bounds__(256, 2) void gemm_bt(const unsigned short* __restrict__ A,
                                                  const unsigned short* __restrict__ B,
                                                  float* __restrict__ C) {
  __shared__ unsigned short sh[4 * 8192];   // 4 bufs x (A:4096 | B:4096 elems) = 64 KB

  const int t = threadIdx.x;
  const int lane = t & 63;
  const int wave = t >> 6;
  const int wm = wave >> 1, wn = wave & 1;

  // XCD-aware bijective swizzle: 512 wg, 8 XCDs -> 64 wg chunks; chunk walks
  // 16 M-tiles sharing one B panel (L2-resident).
  const int flat = blockIdx.y * gridDim.x + blockIdx.x;   // 0..511
  const int swz = (flat & 7) * 64 + (flat >> 3);
  const int m0 = (swz & 15) * BM;
  const int n0 = (swz >> 4) * BN;

  f32x4_t acc[4][4];
#pragma unroll
  for (int i = 0; i < 4; ++i)
#pragma unroll
    for (int j = 0; j < 4; ++j) acc[i][j] = (f32x4_t){0.f, 0.f, 0.f, 0.f};

  // staging: granule g = q*256+t; row r = g>>2; slot s = g&3 holds source
  // granule c = s ^ ((r>>1)&3)  (involution; LDS dest stays linear).
  size_t goff[2];
  int ldso[2];
#pragma unroll
  for (int q = 0; q < 2; ++q) {
    const int g = q * 256 + t;
    const int rr = g >> 2;
    const int cc = (g & 3) ^ ((rr >> 1) & 3);
    goff[q] = (size_t)rr * K_DIM + (size_t)cc * 8;   // elements
    ldso[q] = (q * 256 + (t & ~63)) * 8;             // wave-uniform base, elements
  }

  // ds_read: fragment (row r, k-granule g=lane>>4) lives at slot g ^ ((r>>1)&3)
  int aofs[4], bofs[4];
#pragma unroll
  for (int i = 0; i < 4; ++i) {
    const int rA = wm * 64 + i * 16 + (lane & 15);
    aofs[i] = rA * 32 + (((lane >> 4) ^ ((rA >> 1) & 3)) * 8);
    const int rB = wn * 64 + i * 16 + (lane & 15);
    bofs[i] = rB * 32 + (((lane >> 4) ^ ((rB >> 1) & 3)) * 8);
  }

  const unsigned short* Ab = A + (size_t)m0 * K_DIM;
  const unsigned short* Bb = B + (size_t)n0 * K_DIM;

  auto stage = [&](int buf, int kk) {
    const int base = buf * 8192;
    async16(Ab + goff[0] + kk, &sh[base + ldso[0]]);
    async16(Ab + goff[1] + kk, &sh[base + ldso[1]]);
    async16(Bb + goff[0] + kk, &sh[base + 4096 + ldso[0]]);
    async16(Bb + goff[1] + kk, &sh[base + 4096 + ldso[1]]);
  };

  auto compute = [&](int buf) {
    const unsigned short* Ax = sh + buf * 8192;
    const unsigned short* Bx = Ax + 4096;
    bf16x8_t af[4], bfr[4];
#pragma unroll
    for (int i = 0; i < 4; ++i) af[i] = *(const bf16x8_t*)&Ax[aofs[i]];
#pragma unroll
    for (int j = 0; j < 4; ++j) bfr[j] = *(const bf16x8_t*)&Bx[bofs[j]];
    __builtin_amdgcn_s_setprio(1);
#pragma unroll
    for (int i = 0; i < 4; ++i)
#pragma unroll
      for (int j = 0; j < 4; ++j)
        acc[i][j] = __builtin_amdgcn_mfma_f32_16x16x32_bf16(af[i], bfr[j],
                                                            acc[i][j], 0, 0, 0);
    __builtin_amdgcn_s_setprio(0);
  };

  // prologue: stage tiles 0,1,2 into bufs 0,1,2
  stage(0, 0);
  stage(1, BK);
  stage(2, 2 * BK);
  int kk = 3 * BK;
  for (int it = 0; it < NTILES - 3; ++it) {
    __builtin_amdgcn_s_barrier();                       // B1: WAR guard
    stage((it + 3) & 3, kk); kk += BK;
    asm volatile("s_waitcnt vmcnt(12)" ::: "memory");   // tile it landed (own)
    __builtin_amdgcn_s_barrier();                       // B2: RAW guard (all waves)
    compute(it & 3);
  }
  // tail: tiles 341,342,343 (no more stages)
  asm volatile("s_waitcnt vmcnt(8)" ::: "memory");
  __builtin_amdgcn_s_barrier();
  compute((NTILES - 3) & 3);
  asm volatile("s_waitcnt vmcnt(4)" ::: "memory");
  __builtin_amdgcn_s_barrier();
  compute((NTILES - 2) & 3);
  asm volatile("s_waitcnt vmcnt(0)" ::: "memory");
  __builtin_amdgcn_s_barrier();
  compute((NTILES - 1) & 3);

#pragma unroll
  for (int i = 0; i < 4; ++i) {
    const int rbase = m0 + wm * 64 + i * 16 + (lane >> 4) * 4;
#pragma unroll
    for (int j = 0; j < 4; ++j) {
      const int col = n0 + wn * 64 + j * 16 + (lane & 15);
#pragma unroll
      for (int rr = 0; rr < 4; ++rr)
        C[(size_t)(rbase + rr) * N_DIM + col] = acc[i][j][rr];
    }
  }
}

// ---------------- launcher ----------------
extern "C" void kernel_launch(void* const* d_in, const int* in_sizes, int n_in,
                              void* d_out, int out_size, void* d_ws, size_t ws_size,
                              hipStream_t stream) {
  const float* x = (const float*)d_in[0];   // [1,2048,11008]
  const float* w = (const float*)d_in[1];   // [4096,11008]
  float* out = (float*)d_out;
  float* true_val = out;                                // 2048*4096
  float* filt = out + (size_t)M_DIM * N_DIM;            // 4096*4403

  char* ws = (char*)d_ws;
  unsigned short* xb = (unsigned short*)ws;                       // 45,088,768 B
  unsigned short* wb = (unsigned short*)(ws + 45088768);          // 90,177,536 B
  int* counts = (int*)(ws + 45088768 + 90177536);                 // 44,032 B
  int* rnk    = counts + NN;                                      // 44,032 B
  int* posn   = rnk + NN;                                         // 44,032 B (16B-aligned)
  int* bhist  = posn + NN;                                        // 43*2049*4 B
  int* pre    = bhist + NCHUNK * NBINS;                           // 43*2049*4 B

  // vote bitmask (344*2048 u32 = 2.8 MB) staged in the true_value output
  // region, which gemm_bt fully overwrites afterwards.
  unsigned* maskT = (unsigned*)true_val;

  // order: cvt_x warms x in L3 for topk; cvt_w warms w for scatter_w.
  cvt_f32_bf16<<<4096, 256, 0, stream>>>((const float4*)x, (ushort4*)xb, M_DIM * K_DIM / 4);
  topk_rows<<<M_DIM, 256, 0, stream>>>(x, maskT);
  cvt_f32_bf16<<<4096, 256, 0, stream>>>((const float4*)w, (ushort4*)wb, N_DIM * K_DIM / 4);
  count_votes<<<NWORDS, 256, 0, stream>>>(maskT, counts);
  count_hist<<<NCHUNK, 256, 0, stream>>>(counts, bhist, rnk);
  scan_hist<<<1, 256, 0, stream>>>(bhist, pre);
  place<<<NCHUNK, 256, 0, stream>>>(counts, rnk, pre, posn);
  scatter_w<<<N_DIM, 256, 0, stream>>>((const float4*)w, (const int4*)posn, filt);

  gemm_bt<<<dim3(N_DIM / BN, M_DIM / BM), 256, 0, stream>>>(xb, wb, true_val);
}

// Round 4
// 869.094 us; speedup vs baseline: 1.0842x; 1.0842x over previous
//
#include <hip/hip_runtime.h>
#include <stdint.h>

#define M_DIM 2048
#define N_DIM 4096
#define K_DIM 11008
#define NN    11008
#define KTOK  2201    // int(11008*0.2)
#define NSEL  4403    // int(11008*0.4)
#define NCHUNK 43     // 43*256 == 11008
#define NCH_P  44     // padded chunk stride for transposed hist
#define NBINS 2049    // counts in [0,2048]
#define NWORDS 344    // 11008/32 mask words per row
#define NC64  172     // 11008/64 ballot chunks per row

typedef __bf16 bf16x8_t __attribute__((ext_vector_type(8)));
typedef float  f32x4_t  __attribute__((ext_vector_type(4)));

__device__ __forceinline__ unsigned short f2bf(float f) {
  unsigned u = __float_as_uint(f);
  u = (u + 0x7FFFu + ((u >> 16) & 1u)) >> 16;   // round-to-nearest-even
  return (unsigned short)u;
}

__device__ __forceinline__ unsigned fkey(unsigned v) {
  return v ^ ((unsigned)((int)v >> 31) | 0x80000000u);
}

// ---------------- f32 -> bf16 conversion (vectorized) ----------------
__global__ __launch_bounds__(256) void cvt_f32_bf16(const float4* __restrict__ src,
                                                    ushort4* __restrict__ dst, int n4) {
  int i = blockIdx.x * 256 + threadIdx.x;
  int stride = gridDim.x * 256;
  for (; i < n4; i += stride) {
    float4 v = src[i];
    ushort4 o;
    o.x = f2bf(v.x); o.y = f2bf(v.y); o.z = f2bf(v.z); o.w = f2bf(v.w);
    dst[i] = o;
  }
}

// ---------------- per-row top-KTOK -> per-row bitmask (radix select) ---------
// v3: register-resident keys. Each thread holds 43 keys (layout i = j*256+t),
// loaded from global ONCE. All radix passes + ballot passes run on registers.
__global__ __launch_bounds__(256) void topk_rows(const float* __restrict__ x,
                                                 unsigned* __restrict__ maskT) {
  __shared__ int hist[2048];        // 8192 B
  __shared__ int wtot[4];
  __shared__ int eqpre[NC64];
  __shared__ int eqex[NC64];
  __shared__ unsigned s_band;
  __shared__ int s_kneed;

  const int t = threadIdx.x;
  const int lane = t & 63;
  const int w = t >> 6;
  const int r = blockIdx.x;
  const unsigned* __restrict__ rowu = (const unsigned*)(x + (size_t)r * NN);

  unsigned kreg[43];
#pragma unroll
  for (int j = 0; j < 43; ++j) kreg[j] = fkey(rowu[j * 256 + t]);

  unsigned band_prefix = 0;
  int kneed = KTOK;

  for (int pass = 0; pass < 3; ++pass) {
    const int bins  = (pass == 2) ? 1024 : 2048;

    for (int i = t; i < bins; i += 256) hist[i] = 0;
    __syncthreads();

    if (pass == 0) {
#pragma unroll
      for (int j = 0; j < 43; ++j) atomicAdd(&hist[kreg[j] >> 21], 1);
    } else if (pass == 1) {
#pragma unroll
      for (int j = 0; j < 43; ++j) {
        unsigned k = kreg[j];
        if ((k >> 21) == band_prefix) atomicAdd(&hist[(k >> 10) & 2047u], 1);
      }
    } else {
#pragma unroll
      for (int j = 0; j < 43; ++j) {
        unsigned k = kreg[j];
        if ((k >> 10) == band_prefix) atomicAdd(&hist[k & 1023u], 1);
      }
    }
    __syncthreads();

    const int nch = bins / 8;
    const int nw  = nch >> 6;
    int loc = 0;
    if (t < nch) {
#pragma unroll
      for (int v = 0; v < 8; ++v) loc += hist[t * 8 + v];
    }
    int incl = loc;
#pragma unroll
    for (int d = 1; d < 64; d <<= 1) {
      int o = __shfl_down(incl, d);
      if (lane + d < 64) incl += o;
    }
    if (w < nw && lane == 0) wtot[w] = incl;
    __syncthreads();
    int wsuf = 0;
    for (int u = w + 1; u < nw; ++u) wsuf += wtot[u];
    const int suf_ex = wsuf + (incl - loc);
    if (t < nch && suf_ex < kneed && suf_ex + loc >= kneed) {
      int run = suf_ex;
      for (int v = t * 8 + 7;; --v) {
        int h = hist[v];
        if (run + h >= kneed) { s_band = (unsigned)v; s_kneed = kneed - run; break; }
        run += h;
      }
    }
    __syncthreads();
    band_prefix = (pass == 0) ? s_band
                : (band_prefix << ((pass == 1) ? 11 : 10)) | s_band;
    kneed = s_kneed;
    __syncthreads();
  }

  const unsigned Tkey = band_prefix;
  const int need = kneed;

#pragma unroll
  for (int it = 0; it < 43; ++it) {
    const int c = 4 * it + w;
    unsigned long long eb = __ballot(kreg[it] == Tkey);
    if (lane == 0) eqpre[c] = __popcll(eb);
  }
  __syncthreads();
  if (t < NC64) {
    int s = 0;
    for (int c = 0; c < t; ++c) s += eqpre[c];
    eqex[t] = s;
  }
  __syncthreads();

#pragma unroll
  for (int it = 0; it < 43; ++it) {
    const int c = 4 * it + w;
    const unsigned k = kreg[it];
    const bool eq = (k == Tkey);
    unsigned long long eb = __ballot(eq);
    int myrank = eqex[c] + __popcll(eb & ((1ull << lane) - 1ull));
    bool pred = (k > Tkey) || (eq && (myrank < need));
    unsigned long long pb = __ballot(pred);
    if (lane == 0) maskT[(size_t)(2 * c)     * M_DIM + r] = (unsigned)pb;
    if (lane == 1) maskT[(size_t)(2 * c + 1) * M_DIM + r] = (unsigned)(pb >> 32);
  }
}

// ---------------- bit-count votes: counts[n] = sum_r maskT bit ----------------
__global__ __launch_bounds__(256) void count_votes(const unsigned* __restrict__ maskT,
                                                   int* __restrict__ counts) {
  __shared__ int part[256 * 33];
  const int t = threadIdx.x;
  const int w = blockIdx.x;
  int c[32];
#pragma unroll
  for (int b = 0; b < 32; ++b) c[b] = 0;
  const unsigned* col = maskT + (size_t)w * M_DIM;
#pragma unroll
  for (int rep = 0; rep < M_DIM / 256; ++rep) {
    unsigned m = col[rep * 256 + t];
#pragma unroll
    for (int b = 0; b < 32; ++b) c[b] += (m >> b) & 1u;
  }
#pragma unroll
  for (int b = 0; b < 32; ++b) part[t * 33 + b] = c[b];
  __syncthreads();
  if (t < 32) {
    int s = 0;
    for (int j = 0; j < 256; ++j) s += part[j * 33 + t];
    counts[w * 32 + t] = s;
  }
}

// ---------------- stable counting sort of counts (desc value, asc index) -----
// v2: histogram stored TRANSPOSED bhistT[bin*44 + chunk] so per-bin data is
// contiguous for scan_hist.
__global__ __launch_bounds__(256) void count_hist(const int* __restrict__ counts,
                                                  int* __restrict__ bhistT,
                                                  int* __restrict__ rnk) {
  __shared__ int lc[256];
  __shared__ int lh[NBINS];
  const int b = blockIdx.x, t = threadIdx.x;
  const int n = b * 256 + t;
  const int c = counts[n];
  lc[t] = c;
  for (int i = t; i < NBINS; i += 256) lh[i] = 0;
  __syncthreads();
  atomicAdd(&lh[c], 1);
  __syncthreads();
  for (int i = t; i < NBINS; i += 256) bhistT[i * NCH_P + b] = lh[i];
  int rk = 0;
  for (int m = 0; m < t; ++m) rk += (lc[m] == c);
  rnk[n] = rk;
}

// scan_hist v2: one block, 1024 threads. Phase1: per-bin totals (contiguous).
// Phase2: parallel suffix scan (shuffle + wave offsets) replacing the serial
// 2049-iteration t==0 loop. Phase3: per-bin running prefix over chunks
// (contiguous reads/writes).
__global__ __launch_bounds__(1024) void scan_hist(const int* __restrict__ bhistT,
                                                  int* __restrict__ preT) {
  __shared__ int total[NBINS];
  __shared__ int sstart[NBINS];
  __shared__ int wsum[16];
  const int t = threadIdx.x;
  const int lane = t & 63;
  const int w = t >> 6;

  for (int c = t; c < NBINS; c += 1024) {
    int s = 0;
#pragma unroll
    for (int h = 0; h < NCHUNK; ++h) s += bhistT[c * NCH_P + h];
    total[c] = s;
  }
  __syncthreads();

  // suffix over c == prefix over j = 2048 - c. Thread t owns j = 2t, 2t+1.
  const int v0 = total[2048 - 2 * t];          // j = 2t
  const int v1 = total[2048 - (2 * t + 1)];    // j = 2t+1 (<= 2047 for t<1024)
  const int pair = v0 + v1;
  int incl = pair;
#pragma unroll
  for (int d = 1; d < 64; d <<= 1) {
    int o = __shfl_up(incl, d);
    if (lane >= d) incl += o;
  }
  if (lane == 63) wsum[w] = incl;
  __syncthreads();
  int woff = 0;
  for (int u = 0; u < w; ++u) woff += wsum[u];
  const int base = woff + (incl - pair);       // exclusive prefix at j = 2t
  sstart[2048 - 2 * t] = base;
  sstart[2048 - (2 * t + 1)] = base + v0;
  if (t == 0) {                                // c = 0 (j = 2048)
    int g = 0;
    for (int u = 0; u < 16; ++u) g += wsum[u];
    sstart[0] = g;
  }
  __syncthreads();

  for (int c = t; c < NBINS; c += 1024) {
    int run = sstart[c];
#pragma unroll
    for (int h = 0; h < NCHUNK; ++h) {
      preT[c * NCH_P + h] = run;
      run += bhistT[c * NCH_P + h];
    }
  }
}

__global__ __launch_bounds__(256) void place(const int* __restrict__ counts,
                                             const int* __restrict__ rnk,
                                             const int* __restrict__ preT,
                                             int* __restrict__ sel) {
  const int b = blockIdx.x, t = threadIdx.x;
  const int n = b * 256 + t;
  const int c = counts[n];
  const int pos = preT[c * NCH_P + b] + rnk[n];
  if (pos < NSEL) sel[pos] = n;
}

// ---------------- gather filtered_W (R1-measured variant) ----------------
__global__ __launch_bounds__(256) void gather_w(const float* __restrict__ w,
                                                const int* __restrict__ sel,
                                                float* __restrict__ out) {
  const int j = blockIdx.x * 256 + threadIdx.x;
  const int d = blockIdx.y;
  if (j < NSEL) out[(size_t)d * NSEL + j] = w[(size_t)d * NN + sel[j]];
}

// ---------------- bf16 MFMA GEMM: C[M][N] = A[M][K] * B[N][K]^T ----------------
// v4 = R1 geometry (BK=64, 2 LDS buffers, 64 KB, full-128B-line staging) with
// ONLY the sync scheme changed: raw s_barrier pair + counted s_waitcnt
// vmcnt(8) replaces __syncthreads' vmcnt(0) drain, so the next tile's 8
// global_load_lds stay in flight across the compute phase (T4).
// Hazards: B1 = WAR guard (compute(t-1)'s ds_reads retired before its
// lgkmcnt-gated MFMAs, which precede B1); per-wave vmcnt(8) then B2 = RAW
// guard (all waves' tile-t loads landed). Same XOR swizzle as R1 (measured
// 0 bank conflicts).
#define BM 128
#define BN 128
#define BK 64
#define NTILES 172   // K_DIM / BK

__device__ __forceinline__ void async16(const void* g, void* l) {
  __builtin_amdgcn_global_load_lds(
      (const __attribute__((address_space(1))) void*)g,
      (__attribute__((address_space(3))) void*)l, 16, 0, 0);
}

__global__ __launch_bounds__(256, 2) void gemm_bt(const unsigned short* __restrict__ A,
                                                  const unsigned short* __restrict__ B,
                                                  float* __restrict__ C) {
  __shared__ unsigned short sh[2][2][BM * BK];   // [buf][A/B][8192] = 64 KB

  const int t = threadIdx.x;
  const int lane = t & 63;
  const int wave = t >> 6;
  const int wm = wave >> 1, wn = wave & 1;

  // XCD-aware bijective swizzle: 512 wg, 8 XCDs -> 64 wg chunks; chunk walks
  // 16 M-tiles sharing one B panel (L2-resident).
  const int flat = blockIdx.y * gridDim.x + blockIdx.x;   // 0..511
  const int swz = (flat & 7) * 64 + (flat >> 3);
  const int m0 = (swz & 15) * BM;
  const int n0 = (swz >> 4) * BN;

  f32x4_t acc[4][4];
#pragma unroll
  for (int i = 0; i < 4; ++i)
#pragma unroll
    for (int j = 0; j < 4; ++j) acc[i][j] = (f32x4_t){0.f, 0.f, 0.f, 0.f};

  // staging: granule g = q*256+t; row r = g>>3; slot g&7 holds source granule
  // (g&7)^(r&7)  (involution; LDS dest linear per rule 21).
  size_t goff[4];
  int ldso[4];
#pragma unroll
  for (int q = 0; q < 4; ++q) {
    const int g = q * 256 + t;
    const int rr = g >> 3;
    const int cc = (g & 7) ^ (rr & 7);
    goff[q] = (size_t)rr * K_DIM + (size_t)cc * 8;   // elements
    ldso[q] = (q * 256 + (t & ~63)) * 8;             // wave-uniform base, elements
  }

  // ds_read: fragment (row r, k-granule g = s*4+(lane>>4)) at slot g^(r&7).
  int aofs[2][4], bofs[2][4];
#pragma unroll
  for (int s = 0; s < 2; ++s)
#pragma unroll
    for (int i = 0; i < 4; ++i) {
      const int rA = wm * 64 + i * 16 + (lane & 15);
      aofs[s][i] = rA * 64 + (((s * 4 + (lane >> 4)) ^ (rA & 7)) * 8);
      const int rB = wn * 64 + i * 16 + (lane & 15);
      bofs[s][i] = rB * 64 + (((s * 4 + (lane >> 4)) ^ (rB & 7)) * 8);
    }

  const unsigned short* Ab = A + (size_t)m0 * K_DIM;
  const unsigned short* Bb = B + (size_t)n0 * K_DIM;

  auto stage = [&](int buf, int kk) {
#pragma unroll
    for (int q = 0; q < 4; ++q)
      async16(Ab + goff[q] + kk, &sh[buf][0][ldso[q]]);
#pragma unroll
    for (int q = 0; q < 4; ++q)
      async16(Bb + goff[q] + kk, &sh[buf][1][ldso[q]]);
  };

  auto compute = [&](int buf) {
    const unsigned short* Ax = sh[buf][0];
    const unsigned short* Bx = sh[buf][1];
#pragma unroll
    for (int s = 0; s < 2; ++s) {
      bf16x8_t af[4], bfr[4];
#pragma unroll
      for (int i = 0; i < 4; ++i) af[i] = *(const bf16x8_t*)&Ax[aofs[s][i]];
#pragma unroll
      for (int j = 0; j < 4; ++j) bfr[j] = *(const bf16x8_t*)&Bx[bofs[s][j]];
      __builtin_amdgcn_s_setprio(1);
#pragma unroll
      for (int i = 0; i < 4; ++i)
#pragma unroll
        for (int j = 0; j < 4; ++j)
          acc[i][j] = __builtin_amdgcn_mfma_f32_16x16x32_bf16(af[i], bfr[j],
                                                              acc[i][j], 0, 0, 0);
      __builtin_amdgcn_s_setprio(0);
    }
  };

  // 172 tiles, manual 2x unroll for literal buffer indices.
  stage(0, 0);
  int kk = BK;
  for (int p = 0; p < 85; ++p) {                      // computes tiles 0..169
    __builtin_amdgcn_s_barrier();                     // B1: WAR
    stage(1, kk); kk += BK;
    asm volatile("s_waitcnt vmcnt(8)" ::: "memory");  // even tile landed
    __builtin_amdgcn_s_barrier();                     // B2: RAW
    compute(0);
    __builtin_amdgcn_s_barrier();                     // B1
    stage(0, kk); kk += BK;
    asm volatile("s_waitcnt vmcnt(8)" ::: "memory");  // odd tile landed
    __builtin_amdgcn_s_barrier();                     // B2
    compute(1);
  }
  __builtin_amdgcn_s_barrier();
  stage(1, kk);                                       // tile 171
  asm volatile("s_waitcnt vmcnt(8)" ::: "memory");
  __builtin_amdgcn_s_barrier();
  compute(0);                                         // tile 170
  asm volatile("s_waitcnt vmcnt(0)" ::: "memory");
  __builtin_amdgcn_s_barrier();
  compute(1);                                         // tile 171

#pragma unroll
  for (int i = 0; i < 4; ++i) {
    const int rbase = m0 + wm * 64 + i * 16 + (lane >> 4) * 4;
#pragma unroll
    for (int j = 0; j < 4; ++j) {
      const int col = n0 + wn * 64 + j * 16 + (lane & 15);
#pragma unroll
      for (int rr = 0; rr < 4; ++rr)
        C[(size_t)(rbase + rr) * N_DIM + col] = acc[i][j][rr];
    }
  }
}

// ---------------- launcher ----------------
extern "C" void kernel_launch(void* const* d_in, const int* in_sizes, int n_in,
                              void* d_out, int out_size, void* d_ws, size_t ws_size,
                              hipStream_t stream) {
  const float* x = (const float*)d_in[0];   // [1,2048,11008]
  const float* w = (const float*)d_in[1];   // [4096,11008]
  float* out = (float*)d_out;
  float* true_val = out;                                // 2048*4096
  float* filt = out + (size_t)M_DIM * N_DIM;            // 4096*4403

  char* ws = (char*)d_ws;
  unsigned short* xb = (unsigned short*)ws;                       // 45,088,768 B
  unsigned short* wb = (unsigned short*)(ws + 45088768);          // 90,177,536 B
  int* counts = (int*)(ws + 45088768 + 90177536);                 // 44,032 B
  int* rnk    = counts + NN;                                      // 44,032 B
  int* bhistT = rnk + NN;                                         // 2049*44*4 B
  int* preT   = bhistT + NBINS * NCH_P;                           // 2049*44*4 B
  int* sel    = preT + NBINS * NCH_P;                             // 17,612 B

  // vote bitmask (344*2048 u32 = 2.8 MB) staged in the true_value output
  // region, which gemm_bt fully overwrites afterwards.
  unsigned* maskT = (unsigned*)true_val;

  // order: cvt_x warms x in L3 for topk; cvt_w warms w for gather_w.
  cvt_f32_bf16<<<4096, 256, 0, stream>>>((const float4*)x, (ushort4*)xb, M_DIM * K_DIM / 4);
  topk_rows<<<M_DIM, 256, 0, stream>>>(x, maskT);
  cvt_f32_bf16<<<4096, 256, 0, stream>>>((const float4*)w, (ushort4*)wb, N_DIM * K_DIM / 4);
  count_votes<<<NWORDS, 256, 0, stream>>>(maskT, counts);
  count_hist<<<NCHUNK, 256, 0, stream>>>(counts, bhistT, rnk);
  scan_hist<<<1, 1024, 0, stream>>>(bhistT, preT);
  place<<<NCHUNK, 256, 0, stream>>>(counts, rnk, preT, sel);
  gather_w<<<dim3((NSEL + 255) / 256, N_DIM), 256, 0, stream>>>(w, sel, filt);

  gemm_bt<<<dim3(N_DIM / BN, M_DIM / BM), 256, 0, stream>>>(xb, wb, true_val);
}